// Round 2
// baseline (266.368 us; speedup 1.0000x reference)
//
#include <hip/hip_runtime.h>
#include <hip/hip_bf16.h>

#define N_NODES 100000
#define DEG 16
#define NT16 6250             // 16-row tiles (100000/16)
#define NG64 1563             // 64-row groups (ceil)
#define G1_BLOCKS 782         // 3128 waves -> exactly <=2 tiles/wave
#define G1_WSTRIDE (G1_BLOCKS * 4)

typedef __attribute__((ext_vector_type(8))) short short8;   // 8 bf16
typedef __attribute__((ext_vector_type(4))) float f32x4;
// raw ext-vector types for __builtin_nontemporal_* (HIP struct vectors not accepted)
typedef __attribute__((ext_vector_type(4))) float f4raw;
typedef __attribute__((ext_vector_type(4))) int   i4raw;
typedef __attribute__((ext_vector_type(4))) unsigned u4raw;

__device__ inline unsigned short f2bf(float f) {
    union { float f; unsigned u; } v; v.f = f;
    unsigned u = v.u;
    u += 0x7FFFu + ((u >> 16) & 1u);    // RNE
    return (unsigned short)(u >> 16);
}
__device__ inline unsigned pk2bf(float a, float b) {        // HW v_cvt_pk_bf16_f32 (RNE)
    union { __hip_bfloat162 b2; unsigned u; } v;
    v.b2 = __float22bfloat162_rn(make_float2(a, b));
    return v.u;
}
__device__ inline float bflo(unsigned u) {
    union { unsigned u; float f; } v; v.u = u << 16; return v.f;
}
__device__ inline float bfhi(unsigned u) {
    union { unsigned u; float f; } v; v.u = u & 0xFFFF0000u; return v.f;
}

// ---------------------------------------------------------------------------
// GEMM1: h[M,64](bf16) = X[M,256](fp32) @ W1[256,64](fp32).
// Half-tile software pipeline (spill-free, verified R6/R7); 2 tiles/wave.
// X loads are NON-TEMPORAL: X is stream-once; keep L2 free for the h writes
// so spmm_gemm2 finds h resident. LDS = 41 KB -> 3 blocks/CU.
// ---------------------------------------------------------------------------
__global__ __launch_bounds__(256) void gemm1_k256(const float* __restrict__ X,
                                                  const float* __restrict__ W1,
                                                  unsigned short* __restrict__ h)
{
    __shared__ unsigned short wfrag[256 * 64];      // 32 KB, B-fragment order
    __shared__ unsigned short estage[4][16 * 72];   //  9 KB, per-wave epilogue

    const int tid  = threadIdx.x;
    const int lane = tid & 63;
    const int wid  = tid >> 6;
    const int q    = lane >> 4;
    const int l16  = lane & 15;

    // ---- W1 staging: rows kg*4..+3, cols cq*16..+15 per thread ----
    {
        const int kg = tid >> 2;          // 0..63
        const int cq = tid & 3;           // col quarter
        float4 wr[16];
        #pragma unroll
        for (int r = 0; r < 4; ++r)
            #pragma unroll
            for (int i = 0; i < 4; ++i)
                wr[r * 4 + i] = *(const float4*)(W1 + (kg * 4 + r) * 64 + cq * 16 + i * 4);
        const int kb  = kg >> 3;
        const int lnr = (((kg * 4) >> 3) & 3) * 16;
        const int jb  = (kg * 4) & 7;
        #pragma unroll
        for (int c = 0; c < 16; ++c) {
            ushort4 w4;
            #pragma unroll
            for (int r = 0; r < 4; ++r) {
                float4 v = wr[r * 4 + (c >> 2)];
                float  f = ((c & 3) == 0) ? v.x : ((c & 3) == 1) ? v.y :
                           ((c & 3) == 2) ? v.z : v.w;
                ((unsigned short*)&w4)[r] = f2bf(f);
            }
            *(ushort4*)&wfrag[(((kb * 4) + cq) * 64 + lnr + c) * 8 + jb] = w4;
        }
    }
    __syncthreads();

    const int bpidx = (((l16 << 2) | q) << 2);   // source lane * 4 for bpermute
    const size_t xoff = (size_t)(lane >> 2) * 256 + (lane & 3) * 8;

    int t = blockIdx.x * 4 + wid;

    f4raw pa[8];                                  // half0: kb = 0..3
    {
        const float* xb = X + (size_t)t * 16 * 256 + xoff;
        #pragma unroll
        for (int kb = 0; kb < 4; ++kb) {
            pa[2 * kb]     = __builtin_nontemporal_load((const f4raw*)(xb + kb * 32));
            pa[2 * kb + 1] = __builtin_nontemporal_load((const f4raw*)(xb + kb * 32 + 4));
        }
    }

    while (t < NT16) {
        const float* xb = X + (size_t)t * 16 * 256 + xoff;
        f4raw pb[8];                              // half1 loads in flight
        #pragma unroll
        for (int kb = 4; kb < 8; ++kb) {
            pb[2 * (kb - 4)]     = __builtin_nontemporal_load((const f4raw*)(xb + kb * 32));
            pb[2 * (kb - 4) + 1] = __builtin_nontemporal_load((const f4raw*)(xb + kb * 32 + 4));
        }

        f32x4 a0 = {0,0,0,0}, a1 = {0,0,0,0}, a2 = {0,0,0,0}, a3 = {0,0,0,0};

        #pragma unroll
        for (int kb = 0; kb < 4; ++kb) {          // compute half0
            union { int u[4]; short8 s; } uu;
            uu.u[0] = __builtin_amdgcn_ds_bpermute(bpidx, (int)pk2bf(pa[2*kb].x,   pa[2*kb].y));
            uu.u[1] = __builtin_amdgcn_ds_bpermute(bpidx, (int)pk2bf(pa[2*kb].z,   pa[2*kb].w));
            uu.u[2] = __builtin_amdgcn_ds_bpermute(bpidx, (int)pk2bf(pa[2*kb+1].x, pa[2*kb+1].y));
            uu.u[3] = __builtin_amdgcn_ds_bpermute(bpidx, (int)pk2bf(pa[2*kb+1].z, pa[2*kb+1].w));
            const short8* wp = (const short8*)&wfrag[(size_t)((kb * 4) * 64 + lane) * 8];
            a0 = __builtin_amdgcn_mfma_f32_16x16x32_bf16(uu.s, wp[0 * 64], a0, 0, 0, 0);
            a1 = __builtin_amdgcn_mfma_f32_16x16x32_bf16(uu.s, wp[1 * 64], a1, 0, 0, 0);
            a2 = __builtin_amdgcn_mfma_f32_16x16x32_bf16(uu.s, wp[2 * 64], a2, 0, 0, 0);
            a3 = __builtin_amdgcn_mfma_f32_16x16x32_bf16(uu.s, wp[3 * 64], a3, 0, 0, 0);
        }

        const int tn = t + G1_WSTRIDE;            // next tile's half0 in flight
        if (tn < NT16) {
            const float* xn = X + (size_t)tn * 16 * 256 + xoff;
            #pragma unroll
            for (int kb = 0; kb < 4; ++kb) {
                pa[2 * kb]     = __builtin_nontemporal_load((const f4raw*)(xn + kb * 32));
                pa[2 * kb + 1] = __builtin_nontemporal_load((const f4raw*)(xn + kb * 32 + 4));
            }
        }

        #pragma unroll
        for (int kb = 4; kb < 8; ++kb) {          // compute half1
            const int i = kb - 4;
            union { int u[4]; short8 s; } uu;
            uu.u[0] = __builtin_amdgcn_ds_bpermute(bpidx, (int)pk2bf(pb[2*i].x,   pb[2*i].y));
            uu.u[1] = __builtin_amdgcn_ds_bpermute(bpidx, (int)pk2bf(pb[2*i].z,   pb[2*i].w));
            uu.u[2] = __builtin_amdgcn_ds_bpermute(bpidx, (int)pk2bf(pb[2*i+1].x, pb[2*i+1].y));
            uu.u[3] = __builtin_amdgcn_ds_bpermute(bpidx, (int)pk2bf(pb[2*i+1].z, pb[2*i+1].w));
            const short8* wp = (const short8*)&wfrag[(size_t)((kb * 4) * 64 + lane) * 8];
            a0 = __builtin_amdgcn_mfma_f32_16x16x32_bf16(uu.s, wp[0 * 64], a0, 0, 0, 0);
            a1 = __builtin_amdgcn_mfma_f32_16x16x32_bf16(uu.s, wp[1 * 64], a1, 0, 0, 0);
            a2 = __builtin_amdgcn_mfma_f32_16x16x32_bf16(uu.s, wp[2 * 64], a2, 0, 0, 0);
            a3 = __builtin_amdgcn_mfma_f32_16x16x32_bf16(uu.s, wp[3 * 64], a3, 0, 0, 0);
        }

        // epilogue: D[q*4+r][ct*16+l16] -> bf16 rows via per-wave LDS
        unsigned short* st = estage[wid];
        #pragma unroll
        for (int r = 0; r < 4; ++r) {
            int rr = (q * 4 + r) * 72 + l16;
            st[rr + 0 * 16] = f2bf(a0[r]);
            st[rr + 1 * 16] = f2bf(a1[r]);
            st[rr + 2 * 16] = f2bf(a2[r]);
            st[rr + 3 * 16] = f2bf(a3[r]);
        }
        #pragma unroll
        for (int i = 0; i < 4; ++i) {
            int row = i * 4 + q;
            uint2 v = *(const uint2*)&st[row * 72 + l16 * 4];
            *(uint2*)(h + (size_t)(t * 16 + row) * 64 + l16 * 4) = v;   // cached: spmm1 reuses
        }
        t = tn;
    }
}

// ---------------------------------------------------------------------------
// Two-row gather, 8 lanes/row x uint4. All 16 random gathers are issued
// BEFORE any accumulate so each thread keeps 16 misses in flight (was 8,
// drained per row). colind/vals loads NON-TEMPORAL (stream-once).
// Peak live set ~120 VGPR: 16x uint4 gathers (64) + 8x f4raw vals (32) +
// 16 acc (16) + addressing — fits the <=128 tier (4 blocks/CU).
// ---------------------------------------------------------------------------
__device__ inline void gather2(const unsigned short* __restrict__ B,
                               const int* __restrict__ ci0,
                               const float* __restrict__ vv0,
                               const int* __restrict__ ci1,
                               const float* __restrict__ vv1,
                               int j8,
                               float* __restrict__ acc0,
                               float* __restrict__ acc1)
{
    // colind for both rows first (addresses), then all 16 gathers, then vals.
    i4raw c0a = __builtin_nontemporal_load((const i4raw*)ci0 + 0);
    i4raw c0b = __builtin_nontemporal_load((const i4raw*)ci0 + 1);
    i4raw c0c = __builtin_nontemporal_load((const i4raw*)ci0 + 2);
    i4raw c0d = __builtin_nontemporal_load((const i4raw*)ci0 + 3);
    i4raw c1a = __builtin_nontemporal_load((const i4raw*)ci1 + 0);
    i4raw c1b = __builtin_nontemporal_load((const i4raw*)ci1 + 1);
    i4raw c1c = __builtin_nontemporal_load((const i4raw*)ci1 + 2);
    i4raw c1d = __builtin_nontemporal_load((const i4raw*)ci1 + 3);

    const int off = j8 * 8;
    uint4 g0  = *(const uint4*)(B + (size_t)c0a.x * 64 + off);
    uint4 g1  = *(const uint4*)(B + (size_t)c0a.y * 64 + off);
    uint4 g2  = *(const uint4*)(B + (size_t)c0a.z * 64 + off);
    uint4 g3  = *(const uint4*)(B + (size_t)c0a.w * 64 + off);
    uint4 g4  = *(const uint4*)(B + (size_t)c0b.x * 64 + off);
    uint4 g5  = *(const uint4*)(B + (size_t)c0b.y * 64 + off);
    uint4 g6  = *(const uint4*)(B + (size_t)c0b.z * 64 + off);
    uint4 g7  = *(const uint4*)(B + (size_t)c0b.w * 64 + off);
    uint4 g8  = *(const uint4*)(B + (size_t)c0c.x * 64 + off);
    uint4 g9  = *(const uint4*)(B + (size_t)c0c.y * 64 + off);
    uint4 g10 = *(const uint4*)(B + (size_t)c0c.z * 64 + off);
    uint4 g11 = *(const uint4*)(B + (size_t)c0c.w * 64 + off);
    uint4 g12 = *(const uint4*)(B + (size_t)c0d.x * 64 + off);
    uint4 g13 = *(const uint4*)(B + (size_t)c0d.y * 64 + off);
    uint4 g14 = *(const uint4*)(B + (size_t)c0d.z * 64 + off);
    uint4 g15 = *(const uint4*)(B + (size_t)c0d.w * 64 + off);
    uint4 h0  = *(const uint4*)(B + (size_t)c1a.x * 64 + off);
    uint4 h1  = *(const uint4*)(B + (size_t)c1a.y * 64 + off);
    uint4 h2  = *(const uint4*)(B + (size_t)c1a.z * 64 + off);
    uint4 h3  = *(const uint4*)(B + (size_t)c1a.w * 64 + off);
    uint4 h4  = *(const uint4*)(B + (size_t)c1b.x * 64 + off);
    uint4 h5  = *(const uint4*)(B + (size_t)c1b.y * 64 + off);
    uint4 h6  = *(const uint4*)(B + (size_t)c1b.z * 64 + off);
    uint4 h7  = *(const uint4*)(B + (size_t)c1b.w * 64 + off);
    uint4 h8  = *(const uint4*)(B + (size_t)c1c.x * 64 + off);
    uint4 h9  = *(const uint4*)(B + (size_t)c1c.y * 64 + off);
    uint4 h10 = *(const uint4*)(B + (size_t)c1c.z * 64 + off);
    uint4 h11 = *(const uint4*)(B + (size_t)c1c.w * 64 + off);
    uint4 h12 = *(const uint4*)(B + (size_t)c1d.x * 64 + off);
    uint4 h13 = *(const uint4*)(B + (size_t)c1d.y * 64 + off);
    uint4 h14 = *(const uint4*)(B + (size_t)c1d.z * 64 + off);
    uint4 h15 = *(const uint4*)(B + (size_t)c1d.w * 64 + off);

    f4raw v0a = __builtin_nontemporal_load((const f4raw*)vv0 + 0);
    f4raw v0b = __builtin_nontemporal_load((const f4raw*)vv0 + 1);
    f4raw v0c = __builtin_nontemporal_load((const f4raw*)vv0 + 2);
    f4raw v0d = __builtin_nontemporal_load((const f4raw*)vv0 + 3);
    f4raw v1a = __builtin_nontemporal_load((const f4raw*)vv1 + 0);
    f4raw v1b = __builtin_nontemporal_load((const f4raw*)vv1 + 1);
    f4raw v1c = __builtin_nontemporal_load((const f4raw*)vv1 + 2);
    f4raw v1d = __builtin_nontemporal_load((const f4raw*)vv1 + 3);

#define ACC8(acc, g, s) \
    acc[0] += (s) * bflo((g).x); acc[1] += (s) * bfhi((g).x); \
    acc[2] += (s) * bflo((g).y); acc[3] += (s) * bfhi((g).y); \
    acc[4] += (s) * bflo((g).z); acc[5] += (s) * bfhi((g).z); \
    acc[6] += (s) * bflo((g).w); acc[7] += (s) * bfhi((g).w);
    ACC8(acc0, g0,  v0a.x) ACC8(acc0, g1,  v0a.y) ACC8(acc0, g2,  v0a.z) ACC8(acc0, g3,  v0a.w)
    ACC8(acc0, g4,  v0b.x) ACC8(acc0, g5,  v0b.y) ACC8(acc0, g6,  v0b.z) ACC8(acc0, g7,  v0b.w)
    ACC8(acc0, g8,  v0c.x) ACC8(acc0, g9,  v0c.y) ACC8(acc0, g10, v0c.z) ACC8(acc0, g11, v0c.w)
    ACC8(acc0, g12, v0d.x) ACC8(acc0, g13, v0d.y) ACC8(acc0, g14, v0d.z) ACC8(acc0, g15, v0d.w)
    ACC8(acc1, h0,  v1a.x) ACC8(acc1, h1,  v1a.y) ACC8(acc1, h2,  v1a.z) ACC8(acc1, h3,  v1a.w)
    ACC8(acc1, h4,  v1b.x) ACC8(acc1, h5,  v1b.y) ACC8(acc1, h6,  v1b.z) ACC8(acc1, h7,  v1b.w)
    ACC8(acc1, h8,  v1c.x) ACC8(acc1, h9,  v1c.y) ACC8(acc1, h10, v1c.z) ACC8(acc1, h11, v1c.w)
    ACC8(acc1, h12, v1d.x) ACC8(acc1, h13, v1d.y) ACC8(acc1, h14, v1d.z) ACC8(acc1, h15, v1d.w)
#undef ACC8
}

// ---------------------------------------------------------------------------
// Fused SpMM1 + ReLU + GEMM2: o1 = bf16( relu(A @ h) @ W2 ).  17 KB LDS.
// Each thread-slot now gathers its TWO rows concurrently (16 misses in
// flight). __launch_bounds__(256,4) pins VGPR<=128 -> 16 waves/CU.
// ---------------------------------------------------------------------------
__global__ __launch_bounds__(256, 4) void spmm_gemm2(const int* __restrict__ colind,
                                                     const float* __restrict__ vals,
                                                     const unsigned short* __restrict__ h,
                                                     const float* __restrict__ W2,
                                                     unsigned short* __restrict__ o1)
{
    __shared__ unsigned short wfrag2[64 * 64];      // 8 KB
    __shared__ unsigned short stage[4][16 * 72];    // 9 KB

    const int tid  = threadIdx.x;
    const int lane = tid & 63;
    const int wid  = tid >> 6;
    const int q    = lane >> 4;
    const int l16  = lane & 15;

    // ---- W2 staging ----
    {
        const int r4 = tid >> 2;
        const int qt = tid & 3;
        float4 wr[4];
        #pragma unroll
        for (int i = 0; i < 4; ++i)
            wr[i] = *(const float4*)(W2 + r4 * 64 + qt * 16 + i * 4);
        const int kb  = r4 >> 5;
        const int j   = r4 & 7;
        const int lnr = ((r4 >> 3) & 3) * 16;
        #pragma unroll
        for (int c = 0; c < 16; ++c) {
            float f = ((c & 3) == 0) ? wr[c >> 2].x :
                      ((c & 3) == 1) ? wr[c >> 2].y :
                      ((c & 3) == 2) ? wr[c >> 2].z : wr[c >> 2].w;
            wfrag2[(((kb * 4) + qt) * 64 + lnr + c) * 8 + j] = f2bf(f);
        }
    }
    __syncthreads();

    const int base = blockIdx.x * 64 + wid * 16;    // grid 1563 covers 100032
    unsigned short* st = stage[wid];
    const int rl = lane >> 3;
    const int j8 = lane & 7;

    const int row0 = base + rl;
    const int row1 = base + 8 + rl;
    const int rc0  = row0 < N_NODES ? row0 : N_NODES - 1;
    const int rc1  = row1 < N_NODES ? row1 : N_NODES - 1;
    float acc0[8] = {0.f,0.f,0.f,0.f,0.f,0.f,0.f,0.f};
    float acc1[8] = {0.f,0.f,0.f,0.f,0.f,0.f,0.f,0.f};
    gather2(h, colind + (size_t)rc0 * DEG, vals + (size_t)rc0 * DEG,
               colind + (size_t)rc1 * DEG, vals + (size_t)rc1 * DEG,
            j8, acc0, acc1);

    {
        uint4 pk;
        pk.x = pk2bf(fmaxf(acc0[0], 0.f), fmaxf(acc0[1], 0.f));
        pk.y = pk2bf(fmaxf(acc0[2], 0.f), fmaxf(acc0[3], 0.f));
        pk.z = pk2bf(fmaxf(acc0[4], 0.f), fmaxf(acc0[5], 0.f));
        pk.w = pk2bf(fmaxf(acc0[6], 0.f), fmaxf(acc0[7], 0.f));
        *(uint4*)&st[rl * 72 + j8 * 8] = pk;
        pk.x = pk2bf(fmaxf(acc1[0], 0.f), fmaxf(acc1[1], 0.f));
        pk.y = pk2bf(fmaxf(acc1[2], 0.f), fmaxf(acc1[3], 0.f));
        pk.z = pk2bf(fmaxf(acc1[4], 0.f), fmaxf(acc1[5], 0.f));
        pk.w = pk2bf(fmaxf(acc1[6], 0.f), fmaxf(acc1[7], 0.f));
        *(uint4*)&st[(8 + rl) * 72 + j8 * 8] = pk;
    }
    // wave-private LDS slice: DS ops in-order per wave, no barrier needed

    f32x4 a0 = {0,0,0,0}, a1 = {0,0,0,0}, a2 = {0,0,0,0}, a3 = {0,0,0,0};
    #pragma unroll
    for (int kb = 0; kb < 2; ++kb) {
        short8 af = *(const short8*)&st[l16 * 72 + kb * 32 + q * 8];
        const short8* wp = (const short8*)&wfrag2[(size_t)((kb * 4) * 64 + lane) * 8];
        a0 = __builtin_amdgcn_mfma_f32_16x16x32_bf16(af, wp[0 * 64], a0, 0, 0, 0);
        a1 = __builtin_amdgcn_mfma_f32_16x16x32_bf16(af, wp[1 * 64], a1, 0, 0, 0);
        a2 = __builtin_amdgcn_mfma_f32_16x16x32_bf16(af, wp[2 * 64], a2, 0, 0, 0);
        a3 = __builtin_amdgcn_mfma_f32_16x16x32_bf16(af, wp[3 * 64], a3, 0, 0, 0);
    }
    #pragma unroll
    for (int r = 0; r < 4; ++r) {
        int rr = (q * 4 + r) * 72 + l16;
        st[rr + 0 * 16] = f2bf(a0[r]);
        st[rr + 1 * 16] = f2bf(a1[r]);
        st[rr + 2 * 16] = f2bf(a2[r]);
        st[rr + 3 * 16] = f2bf(a3[r]);
    }
    #pragma unroll
    for (int i = 0; i < 4; ++i) {
        int row = base + i * 4 + q;
        if (row < N_NODES) {
            uint2 v = *(const uint2*)&st[(i * 4 + q) * 72 + l16 * 4];
            *(uint2*)(o1 + (size_t)row * 64 + l16 * 4) = v;   // cached: spmm2 reuses
        }
    }
}

// ---------------------------------------------------------------------------
// SpMM2: out(fp32) = A @ o1(bf16). 64 rows/block (2 rows/slot, 16 gathers
// in flight). Non-temporal out stores (never re-read) keep L2 free for the
// o1 gathers. Grid 1563 covers 100032 with guards. No LDS.
// ---------------------------------------------------------------------------
__global__ __launch_bounds__(256, 4) void spmm_out(const int* __restrict__ colind,
                                                   const float* __restrict__ vals,
                                                   const unsigned short* __restrict__ B,
                                                   float* __restrict__ out)
{
    const int tid  = threadIdx.x;
    const int lane = tid & 63;
    const int wid  = tid >> 6;
    const int rl   = lane >> 3;
    const int j8   = lane & 7;
    const int base = blockIdx.x * 64 + wid * 16;

    const int row0 = base + rl;
    const int row1 = base + 8 + rl;
    const int rc0  = row0 < N_NODES ? row0 : N_NODES - 1;
    const int rc1  = row1 < N_NODES ? row1 : N_NODES - 1;
    float acc0[8] = {0.f,0.f,0.f,0.f,0.f,0.f,0.f,0.f};
    float acc1[8] = {0.f,0.f,0.f,0.f,0.f,0.f,0.f,0.f};
    gather2(B, colind + (size_t)rc0 * DEG, vals + (size_t)rc0 * DEG,
               colind + (size_t)rc1 * DEG, vals + (size_t)rc1 * DEG,
            j8, acc0, acc1);

    if (row0 < N_NODES) {
        f4raw lo = { acc0[0], acc0[1], acc0[2], acc0[3] };
        f4raw hi = { acc0[4], acc0[5], acc0[6], acc0[7] };
        float* op = out + (size_t)row0 * 64 + j8 * 8;
        __builtin_nontemporal_store(lo, (f4raw*)op);
        __builtin_nontemporal_store(hi, (f4raw*)(op + 4));
    }
    if (row1 < N_NODES) {
        f4raw lo = { acc1[0], acc1[1], acc1[2], acc1[3] };
        f4raw hi = { acc1[4], acc1[5], acc1[6], acc1[7] };
        float* op = out + (size_t)row1 * 64 + j8 * 8;
        __builtin_nontemporal_store(lo, (f4raw*)op);
        __builtin_nontemporal_store(hi, (f4raw*)(op + 4));
    }
}

extern "C" void kernel_launch(void* const* d_in, const int* in_sizes, int n_in,
                              void* d_out, int out_size, void* d_ws, size_t ws_size,
                              hipStream_t stream) {
    const float* X      = (const float*)d_in[0];   // [N,256]
    const float* W1     = (const float*)d_in[1];   // [256,64]
    const float* W2     = (const float*)d_in[2];   // [64,64]
    const float* vals   = (const float*)d_in[3];   // [NNZ]
    // d_in[4] = rowptr (fixed degree, unused)
    const int*   colind = (const int*)d_in[5];     // [NNZ]
    float*       out    = (float*)d_out;           // [N,64] fp32

    unsigned short* h  = (unsigned short*)d_ws;        // [N,64] bf16
    unsigned short* o1 = h + (size_t)N_NODES * 64;     // [N,64] bf16 (no alias)

    hipLaunchKernelGGL(gemm1_k256, dim3(G1_BLOCKS), dim3(256), 0, stream, X, W1, h);
    hipLaunchKernelGGL(spmm_gemm2, dim3(NG64), dim3(256), 0, stream,
                       colind, vals, h, W2, o1);
    hipLaunchKernelGGL(spmm_out, dim3(NG64), dim3(256), 0, stream,
                       colind, vals, o1, out);
}

// Round 3
// 232.187 us; speedup vs baseline: 1.1472x; 1.1472x over previous
//
#include <hip/hip_runtime.h>
#include <hip/hip_bf16.h>

#define N_NODES 100000
#define DEG 16
#define NT16 6250             // 16-row tiles (100000/16)
#define NG64 1563             // 64-row groups (ceil)
#define G1_BLOCKS 782         // 3128 waves -> exactly <=2 tiles/wave
#define G1_WSTRIDE (G1_BLOCKS * 4)

typedef __attribute__((ext_vector_type(8))) short short8;   // 8 bf16
typedef __attribute__((ext_vector_type(4))) float f32x4;
// raw ext-vector types for __builtin_nontemporal_* (HIP struct vectors not accepted)
typedef __attribute__((ext_vector_type(4))) float f4raw;
typedef __attribute__((ext_vector_type(4))) int   i4raw;
typedef __attribute__((ext_vector_type(4))) unsigned u4raw;

__device__ inline unsigned short f2bf(float f) {
    union { float f; unsigned u; } v; v.f = f;
    unsigned u = v.u;
    u += 0x7FFFu + ((u >> 16) & 1u);    // RNE
    return (unsigned short)(u >> 16);
}
__device__ inline unsigned pk2bf(float a, float b) {        // HW v_cvt_pk_bf16_f32 (RNE)
    union { __hip_bfloat162 b2; unsigned u; } v;
    v.b2 = __float22bfloat162_rn(make_float2(a, b));
    return v.u;
}
__device__ inline float bflo(unsigned u) {
    union { unsigned u; float f; } v; v.u = u << 16; return v.f;
}
__device__ inline float bfhi(unsigned u) {
    union { unsigned u; float f; } v; v.u = u & 0xFFFF0000u; return v.f;
}

// ---------------------------------------------------------------------------
// GEMM1: h[M,64](bf16) = X[M,256](fp32) @ W1[256,64](fp32).
// Half-tile software pipeline (spill-free, verified R6/R7); 2 tiles/wave.
// X loads are NON-TEMPORAL: X is stream-once; keep L2 free for the h writes
// so spmm_gemm2 finds h resident. LDS = 41 KB -> 3 blocks/CU.
// ---------------------------------------------------------------------------
__global__ __launch_bounds__(256) void gemm1_k256(const float* __restrict__ X,
                                                  const float* __restrict__ W1,
                                                  unsigned short* __restrict__ h)
{
    __shared__ unsigned short wfrag[256 * 64];      // 32 KB, B-fragment order
    __shared__ unsigned short estage[4][16 * 72];   //  9 KB, per-wave epilogue

    const int tid  = threadIdx.x;
    const int lane = tid & 63;
    const int wid  = tid >> 6;
    const int q    = lane >> 4;
    const int l16  = lane & 15;

    // ---- W1 staging: rows kg*4..+3, cols cq*16..+15 per thread ----
    {
        const int kg = tid >> 2;          // 0..63
        const int cq = tid & 3;           // col quarter
        float4 wr[16];
        #pragma unroll
        for (int r = 0; r < 4; ++r)
            #pragma unroll
            for (int i = 0; i < 4; ++i)
                wr[r * 4 + i] = *(const float4*)(W1 + (kg * 4 + r) * 64 + cq * 16 + i * 4);
        const int kb  = kg >> 3;
        const int lnr = (((kg * 4) >> 3) & 3) * 16;
        const int jb  = (kg * 4) & 7;
        #pragma unroll
        for (int c = 0; c < 16; ++c) {
            ushort4 w4;
            #pragma unroll
            for (int r = 0; r < 4; ++r) {
                float4 v = wr[r * 4 + (c >> 2)];
                float  f = ((c & 3) == 0) ? v.x : ((c & 3) == 1) ? v.y :
                           ((c & 3) == 2) ? v.z : v.w;
                ((unsigned short*)&w4)[r] = f2bf(f);
            }
            *(ushort4*)&wfrag[(((kb * 4) + cq) * 64 + lnr + c) * 8 + jb] = w4;
        }
    }
    __syncthreads();

    const int bpidx = (((l16 << 2) | q) << 2);   // source lane * 4 for bpermute
    const size_t xoff = (size_t)(lane >> 2) * 256 + (lane & 3) * 8;

    int t = blockIdx.x * 4 + wid;

    f4raw pa[8];                                  // half0: kb = 0..3
    {
        const float* xb = X + (size_t)t * 16 * 256 + xoff;
        #pragma unroll
        for (int kb = 0; kb < 4; ++kb) {
            pa[2 * kb]     = __builtin_nontemporal_load((const f4raw*)(xb + kb * 32));
            pa[2 * kb + 1] = __builtin_nontemporal_load((const f4raw*)(xb + kb * 32 + 4));
        }
    }

    while (t < NT16) {
        const float* xb = X + (size_t)t * 16 * 256 + xoff;
        f4raw pb[8];                              // half1 loads in flight
        #pragma unroll
        for (int kb = 4; kb < 8; ++kb) {
            pb[2 * (kb - 4)]     = __builtin_nontemporal_load((const f4raw*)(xb + kb * 32));
            pb[2 * (kb - 4) + 1] = __builtin_nontemporal_load((const f4raw*)(xb + kb * 32 + 4));
        }

        f32x4 a0 = {0,0,0,0}, a1 = {0,0,0,0}, a2 = {0,0,0,0}, a3 = {0,0,0,0};

        #pragma unroll
        for (int kb = 0; kb < 4; ++kb) {          // compute half0
            union { int u[4]; short8 s; } uu;
            uu.u[0] = __builtin_amdgcn_ds_bpermute(bpidx, (int)pk2bf(pa[2*kb].x,   pa[2*kb].y));
            uu.u[1] = __builtin_amdgcn_ds_bpermute(bpidx, (int)pk2bf(pa[2*kb].z,   pa[2*kb].w));
            uu.u[2] = __builtin_amdgcn_ds_bpermute(bpidx, (int)pk2bf(pa[2*kb+1].x, pa[2*kb+1].y));
            uu.u[3] = __builtin_amdgcn_ds_bpermute(bpidx, (int)pk2bf(pa[2*kb+1].z, pa[2*kb+1].w));
            const short8* wp = (const short8*)&wfrag[(size_t)((kb * 4) * 64 + lane) * 8];
            a0 = __builtin_amdgcn_mfma_f32_16x16x32_bf16(uu.s, wp[0 * 64], a0, 0, 0, 0);
            a1 = __builtin_amdgcn_mfma_f32_16x16x32_bf16(uu.s, wp[1 * 64], a1, 0, 0, 0);
            a2 = __builtin_amdgcn_mfma_f32_16x16x32_bf16(uu.s, wp[2 * 64], a2, 0, 0, 0);
            a3 = __builtin_amdgcn_mfma_f32_16x16x32_bf16(uu.s, wp[3 * 64], a3, 0, 0, 0);
        }

        const int tn = t + G1_WSTRIDE;            // next tile's half0 in flight
        if (tn < NT16) {
            const float* xn = X + (size_t)tn * 16 * 256 + xoff;
            #pragma unroll
            for (int kb = 0; kb < 4; ++kb) {
                pa[2 * kb]     = __builtin_nontemporal_load((const f4raw*)(xn + kb * 32));
                pa[2 * kb + 1] = __builtin_nontemporal_load((const f4raw*)(xn + kb * 32 + 4));
            }
        }

        #pragma unroll
        for (int kb = 4; kb < 8; ++kb) {          // compute half1
            const int i = kb - 4;
            union { int u[4]; short8 s; } uu;
            uu.u[0] = __builtin_amdgcn_ds_bpermute(bpidx, (int)pk2bf(pb[2*i].x,   pb[2*i].y));
            uu.u[1] = __builtin_amdgcn_ds_bpermute(bpidx, (int)pk2bf(pb[2*i].z,   pb[2*i].w));
            uu.u[2] = __builtin_amdgcn_ds_bpermute(bpidx, (int)pk2bf(pb[2*i+1].x, pb[2*i+1].y));
            uu.u[3] = __builtin_amdgcn_ds_bpermute(bpidx, (int)pk2bf(pb[2*i+1].z, pb[2*i+1].w));
            const short8* wp = (const short8*)&wfrag[(size_t)((kb * 4) * 64 + lane) * 8];
            a0 = __builtin_amdgcn_mfma_f32_16x16x32_bf16(uu.s, wp[0 * 64], a0, 0, 0, 0);
            a1 = __builtin_amdgcn_mfma_f32_16x16x32_bf16(uu.s, wp[1 * 64], a1, 0, 0, 0);
            a2 = __builtin_amdgcn_mfma_f32_16x16x32_bf16(uu.s, wp[2 * 64], a2, 0, 0, 0);
            a3 = __builtin_amdgcn_mfma_f32_16x16x32_bf16(uu.s, wp[3 * 64], a3, 0, 0, 0);
        }

        // epilogue: D[q*4+r][ct*16+l16] -> bf16 rows via per-wave LDS
        unsigned short* st = estage[wid];
        #pragma unroll
        for (int r = 0; r < 4; ++r) {
            int rr = (q * 4 + r) * 72 + l16;
            st[rr + 0 * 16] = f2bf(a0[r]);
            st[rr + 1 * 16] = f2bf(a1[r]);
            st[rr + 2 * 16] = f2bf(a2[r]);
            st[rr + 3 * 16] = f2bf(a3[r]);
        }
        #pragma unroll
        for (int i = 0; i < 4; ++i) {
            int row = i * 4 + q;
            uint2 v = *(const uint2*)&st[row * 72 + l16 * 4];
            *(uint2*)(h + (size_t)(t * 16 + row) * 64 + l16 * 4) = v;   // cached: spmm1 reuses
        }
        t = tn;
    }
}

// ---------------------------------------------------------------------------
// Row gather, 8 lanes/row x uint4; colind/vals loads NON-TEMPORAL (stream-once)
// so they don't evict gather lines from L2.
// ---------------------------------------------------------------------------
__device__ inline void gather_row8(const unsigned short* __restrict__ B,
                                   const int* __restrict__ ci,
                                   const float* __restrict__ vv,
                                   int j8, float* __restrict__ acc)
{
    #pragma unroll
    for (int b = 0; b < 2; ++b) {
        i4raw c0 = __builtin_nontemporal_load((const i4raw*)ci + 2 * b);
        i4raw c1 = __builtin_nontemporal_load((const i4raw*)ci + 2 * b + 1);
        f4raw v0 = __builtin_nontemporal_load((const f4raw*)vv + 2 * b);
        f4raw v1 = __builtin_nontemporal_load((const f4raw*)vv + 2 * b + 1);
        uint4 g0 = *(const uint4*)(B + (size_t)c0.x * 64 + j8 * 8);
        uint4 g1 = *(const uint4*)(B + (size_t)c0.y * 64 + j8 * 8);
        uint4 g2 = *(const uint4*)(B + (size_t)c0.z * 64 + j8 * 8);
        uint4 g3 = *(const uint4*)(B + (size_t)c0.w * 64 + j8 * 8);
        uint4 g4 = *(const uint4*)(B + (size_t)c1.x * 64 + j8 * 8);
        uint4 g5 = *(const uint4*)(B + (size_t)c1.y * 64 + j8 * 8);
        uint4 g6 = *(const uint4*)(B + (size_t)c1.z * 64 + j8 * 8);
        uint4 g7 = *(const uint4*)(B + (size_t)c1.w * 64 + j8 * 8);
#define ACC8(g, s) \
        acc[0] += (s) * bflo((g).x); acc[1] += (s) * bfhi((g).x); \
        acc[2] += (s) * bflo((g).y); acc[3] += (s) * bfhi((g).y); \
        acc[4] += (s) * bflo((g).z); acc[5] += (s) * bfhi((g).z); \
        acc[6] += (s) * bflo((g).w); acc[7] += (s) * bfhi((g).w);
        ACC8(g0, v0.x) ACC8(g1, v0.y) ACC8(g2, v0.z) ACC8(g3, v0.w)
        ACC8(g4, v1.x) ACC8(g5, v1.y) ACC8(g6, v1.z) ACC8(g7, v1.w)
#undef ACC8
    }
}

// ---------------------------------------------------------------------------
// Fused SpMM1 + ReLU + GEMM2: o1 = bf16( relu(A @ h) @ W2 ).  17 KB LDS.
// ---------------------------------------------------------------------------
__global__ __launch_bounds__(256) void spmm_gemm2(const int* __restrict__ colind,
                                                  const float* __restrict__ vals,
                                                  const unsigned short* __restrict__ h,
                                                  const float* __restrict__ W2,
                                                  unsigned short* __restrict__ o1)
{
    __shared__ unsigned short wfrag2[64 * 64];      // 8 KB
    __shared__ unsigned short stage[4][16 * 72];    // 9 KB

    const int tid  = threadIdx.x;
    const int lane = tid & 63;
    const int wid  = tid >> 6;
    const int q    = lane >> 4;
    const int l16  = lane & 15;

    // ---- W2 staging ----
    {
        const int r4 = tid >> 2;
        const int qt = tid & 3;
        float4 wr[4];
        #pragma unroll
        for (int i = 0; i < 4; ++i)
            wr[i] = *(const float4*)(W2 + r4 * 64 + qt * 16 + i * 4);
        const int kb  = r4 >> 5;
        const int j   = r4 & 7;
        const int lnr = ((r4 >> 3) & 3) * 16;
        #pragma unroll
        for (int c = 0; c < 16; ++c) {
            float f = ((c & 3) == 0) ? wr[c >> 2].x :
                      ((c & 3) == 1) ? wr[c >> 2].y :
                      ((c & 3) == 2) ? wr[c >> 2].z : wr[c >> 2].w;
            wfrag2[(((kb * 4) + qt) * 64 + lnr + c) * 8 + j] = f2bf(f);
        }
    }
    __syncthreads();

    const int base = blockIdx.x * 64 + wid * 16;    // grid 1563 covers 100032
    unsigned short* st = stage[wid];
    const int rl = lane >> 3;
    const int j8 = lane & 7;

    #pragma unroll
    for (int p = 0; p < 2; ++p) {
        int lr  = p * 8 + rl;
        int row = base + lr;
        int rc  = row < N_NODES ? row : N_NODES - 1;
        float acc[8] = {0.f,0.f,0.f,0.f,0.f,0.f,0.f,0.f};
        gather_row8(h, colind + (size_t)rc * DEG, vals + (size_t)rc * DEG, j8, acc);
        uint4 pk;
        pk.x = pk2bf(fmaxf(acc[0], 0.f), fmaxf(acc[1], 0.f));
        pk.y = pk2bf(fmaxf(acc[2], 0.f), fmaxf(acc[3], 0.f));
        pk.z = pk2bf(fmaxf(acc[4], 0.f), fmaxf(acc[5], 0.f));
        pk.w = pk2bf(fmaxf(acc[6], 0.f), fmaxf(acc[7], 0.f));
        *(uint4*)&st[lr * 72 + j8 * 8] = pk;
    }
    // wave-private LDS slice: DS ops in-order per wave, no barrier needed

    f32x4 a0 = {0,0,0,0}, a1 = {0,0,0,0}, a2 = {0,0,0,0}, a3 = {0,0,0,0};
    #pragma unroll
    for (int kb = 0; kb < 2; ++kb) {
        short8 af = *(const short8*)&st[l16 * 72 + kb * 32 + q * 8];
        const short8* wp = (const short8*)&wfrag2[(size_t)((kb * 4) * 64 + lane) * 8];
        a0 = __builtin_amdgcn_mfma_f32_16x16x32_bf16(af, wp[0 * 64], a0, 0, 0, 0);
        a1 = __builtin_amdgcn_mfma_f32_16x16x32_bf16(af, wp[1 * 64], a1, 0, 0, 0);
        a2 = __builtin_amdgcn_mfma_f32_16x16x32_bf16(af, wp[2 * 64], a2, 0, 0, 0);
        a3 = __builtin_amdgcn_mfma_f32_16x16x32_bf16(af, wp[3 * 64], a3, 0, 0, 0);
    }
    #pragma unroll
    for (int r = 0; r < 4; ++r) {
        int rr = (q * 4 + r) * 72 + l16;
        st[rr + 0 * 16] = f2bf(a0[r]);
        st[rr + 1 * 16] = f2bf(a1[r]);
        st[rr + 2 * 16] = f2bf(a2[r]);
        st[rr + 3 * 16] = f2bf(a3[r]);
    }
    #pragma unroll
    for (int i = 0; i < 4; ++i) {
        int row = base + i * 4 + q;
        if (row < N_NODES) {
            uint2 v = *(const uint2*)&st[(i * 4 + q) * 72 + l16 * 4];
            *(uint2*)(o1 + (size_t)row * 64 + l16 * 4) = v;   // cached: spmm2 reuses
        }
    }
}

// ---------------------------------------------------------------------------
// SpMM2: out(fp32) = A @ o1(bf16). Grid 3125 exact, no LDS.
// R3: out stores are PLAIN CACHED float4 (was non-temporal). rocprof R2
// showed NT 16B stores write at 64B-line granularity: WRITE_SIZE 101 MB vs
// 25.6 MB ideal (3.96x amplification, ~12 us of HBM time). Each wave writes
// full contiguous 256B row segments, so cached stores merge to full lines.
// ---------------------------------------------------------------------------
__global__ __launch_bounds__(256) void spmm_out(const int* __restrict__ colind,
                                                const float* __restrict__ vals,
                                                const unsigned short* __restrict__ B,
                                                float* __restrict__ out)
{
    const int tid  = threadIdx.x;
    const int lane = tid & 63;
    const int wid  = tid >> 6;
    const int rl   = lane >> 3;
    const int j8   = lane & 7;
    const int row  = blockIdx.x * 32 + wid * 8 + rl;   // 3125*32 = 100000 exact

    float acc[8] = {0.f,0.f,0.f,0.f,0.f,0.f,0.f,0.f};
    gather_row8(B, colind + (size_t)row * DEG, vals + (size_t)row * DEG, j8, acc);

    f4raw lo = { acc[0], acc[1], acc[2], acc[3] };
    f4raw hi = { acc[4], acc[5], acc[6], acc[7] };
    float* op = out + (size_t)row * 64 + j8 * 8;
    *(f4raw*)op       = lo;     // cached: full-line merge in L2
    *(f4raw*)(op + 4) = hi;
}

extern "C" void kernel_launch(void* const* d_in, const int* in_sizes, int n_in,
                              void* d_out, int out_size, void* d_ws, size_t ws_size,
                              hipStream_t stream) {
    const float* X      = (const float*)d_in[0];   // [N,256]
    const float* W1     = (const float*)d_in[1];   // [256,64]
    const float* W2     = (const float*)d_in[2];   // [64,64]
    const float* vals   = (const float*)d_in[3];   // [NNZ]
    // d_in[4] = rowptr (fixed degree, unused)
    const int*   colind = (const int*)d_in[5];     // [NNZ]
    float*       out    = (float*)d_out;           // [N,64] fp32

    unsigned short* h  = (unsigned short*)d_ws;        // [N,64] bf16
    unsigned short* o1 = h + (size_t)N_NODES * 64;     // [N,64] bf16 (no alias)

    hipLaunchKernelGGL(gemm1_k256, dim3(G1_BLOCKS), dim3(256), 0, stream, X, W1, h);
    hipLaunchKernelGGL(spmm_gemm2, dim3(NG64), dim3(256), 0, stream,
                       colind, vals, h, W2, o1);
    hipLaunchKernelGGL(spmm_out, dim3(N_NODES / 32), dim3(256), 0, stream,
                       colind, vals, o1, out);
}